// Round 4
// baseline (192.730 us; speedup 1.0000x reference)
//
#include <hip/hip_runtime.h>

#define HW 4096
#define CC 128
#define NSPLIT 4
#define KEYS_PER_SPLIT (HW / NSPLIT)
#define LOG2E 1.44269504088896f

typedef __bf16 bf16x8 __attribute__((ext_vector_type(8)));
typedef __bf16 bf16x4 __attribute__((ext_vector_type(4)));
typedef __bf16 bf16x2 __attribute__((ext_vector_type(2)));
typedef float floatx4 __attribute__((ext_vector_type(4)));

// ---------------------------------------------------------------------------
// Weight conversion: wq|wk|wv fp32 -> contiguous bf16 [3][128][128]
// ---------------------------------------------------------------------------
__global__ __launch_bounds__(256) void wconv_kernel(
    const float* __restrict__ wq, const float* __restrict__ wk,
    const float* __restrict__ wv, __bf16* __restrict__ wb)
{
    int idx = blockIdx.x * 256 + threadIdx.x;
    int which = idx >> 14;
    int within = idx & 16383;
    const float* src = (which == 0) ? wq : (which == 1) ? wk : wv;
    wb[idx] = (__bf16)src[within];
}

// ---------------------------------------------------------------------------
// Projection. Grid 768 = (n*64+it)*3+m. Q is prescaled by log2(e) so the
// attention softmax can use native exp2 (v_exp_f32) with no per-element mul.
// q,k -> [N][HW][C] bf16; v -> [N][C][HW] bf16.
// ---------------------------------------------------------------------------
__global__ __launch_bounds__(256) void proj_kernel(
    const float* __restrict__ x, const __bf16* __restrict__ wb,
    const float* __restrict__ bq, const float* __restrict__ bk,
    const float* __restrict__ bv,
    __bf16* __restrict__ qb, __bf16* __restrict__ kb, __bf16* __restrict__ vb)
{
    __shared__ char smem_raw[128 * 70 * 2];
    __bf16* Xt = reinterpret_cast<__bf16*>(smem_raw);   // [64][136]
    __bf16* Vt = reinterpret_cast<__bf16*>(smem_raw);   // [128][70]

    const int m   = blockIdx.x % 3;
    const int nit = blockIdx.x / 3;
    const int n   = nit >> 6;
    const int i0  = (nit & 63) << 6;
    const int t   = threadIdx.x;

    const float* xb = x + (size_t)n * CC * HW;

#pragma unroll 4
    for (int p = 0; p < 32; ++p) {
        int c  = p * 4 + (t >> 6);
        int il = t & 63;
        Xt[il * 136 + c] = (__bf16)xb[(size_t)c * HW + i0 + il];
    }
    __syncthreads();

    const int w    = t >> 6;
    const int lane = t & 63;
    const int l16  = lane & 15;
    const int quad = lane >> 4;

    bf16x8 afrag[4];
#pragma unroll
    for (int ks = 0; ks < 4; ++ks)
        afrag[ks] = *reinterpret_cast<const bf16x8*>(
            &Xt[(w * 16 + l16) * 136 + ks * 32 + quad * 8]);

    const __bf16* wm = wb + (size_t)m * CC * CC;
    const float* Bm = (m == 0) ? bq : (m == 1) ? bk : bv;
    const float scale = (m == 0) ? LOG2E : 1.0f;

    if (m < 2) {
        __bf16* dst = (m == 0) ? qb : kb;
#pragma unroll
        for (int h = 0; h < 8; ++h) {
            int d = h * 16 + l16;
            floatx4 acc = {0.f, 0.f, 0.f, 0.f};
#pragma unroll
            for (int ks = 0; ks < 4; ++ks) {
                bf16x8 bfrag = *reinterpret_cast<const bf16x8*>(
                    wm + (size_t)d * CC + ks * 32 + quad * 8);
                acc = __builtin_amdgcn_mfma_f32_16x16x32_bf16(afrag[ks], bfrag, acc, 0, 0, 0);
            }
            float bias = Bm[d];
#pragma unroll
            for (int r = 0; r < 4; ++r) {
                int i = i0 + w * 16 + quad * 4 + r;
                dst[(size_t)n * HW * CC + (size_t)i * CC + d] =
                    (__bf16)((acc[r] + bias) * scale);
            }
        }
    } else {
        __syncthreads();
#pragma unroll
        for (int h = 0; h < 8; ++h) {
            int d = h * 16 + l16;
            floatx4 acc = {0.f, 0.f, 0.f, 0.f};
#pragma unroll
            for (int ks = 0; ks < 4; ++ks) {
                bf16x8 bfrag = *reinterpret_cast<const bf16x8*>(
                    wm + (size_t)d * CC + ks * 32 + quad * 8);
                acc = __builtin_amdgcn_mfma_f32_16x16x32_bf16(afrag[ks], bfrag, acc, 0, 0, 0);
            }
            float bias = Bm[d];
#pragma unroll
            for (int r = 0; r < 4; ++r)
                Vt[d * 70 + w * 16 + quad * 4 + r] = (__bf16)(acc[r] + bias);
        }
        __syncthreads();
#pragma unroll 4
        for (int p = 0; p < 32; ++p) {
            int d  = p * 4 + (t >> 6);
            int il = t & 63;
            vb[((size_t)n * CC + d) * HW + i0 + il] = Vt[d * 70 + il];
        }
    }
}

// ---------------------------------------------------------------------------
// Flash attention, key-split. Grid 512, 128 q/block (32 q/wave).
// S computed in TRANSPOSED orientation (s = mfma(K, Q)): C/D col = q = l16,
// so softmax state is a per-lane scalar and the P^T LDS round-trip is
// 8x b64 packed writes + 4x b128 reads. K staged in LDS; V read direct from
// L2 (536 MB aggregate). O accumulated as O^T[c][q]. exp2 domain throughout.
// ---------------------------------------------------------------------------
#define KT_STRIDE 136                   // bf16; 272 B rows
#define KT_BYTES (64 * KT_STRIDE * 2)   // 17408
#define PT_STRIDE 72                    // bf16; 144 B rows (16B-aligned)
#define PT_WAVE (32 * PT_STRIDE * 2)    // 4608 B per wave
#define T_STRIDE 65                     // fp32 epilogue [c][q]

__global__ __launch_bounds__(256, 3) void attn_split_kernel(
    const __bf16* __restrict__ qb, const __bf16* __restrict__ kb,
    const __bf16* __restrict__ vb,
    __bf16* __restrict__ opart, float* __restrict__ ml)
{
    __shared__ char smem[KT_BYTES + 4 * PT_WAVE];   // 35840 B -> 3 blocks/CU
    __bf16* Kt = reinterpret_cast<__bf16*>(smem);
    float*  T  = reinterpret_cast<float*>(smem);    // epilogue alias [128][65]

    const int b     = blockIdx.x;
    const int n     = (b >> 1) & 3;
    const int split = (((b >> 3) & 1) << 1) | (b & 1);
    const int it    = b >> 4;                 // 0..31
    const int i0    = it << 7;                // *128
    const int t     = threadIdx.x;
    const int w     = t >> 6;
    const int lane  = t & 63;
    const int l16   = lane & 15;
    const int quad  = lane >> 4;

    __bf16* Pt = reinterpret_cast<__bf16*>(smem + KT_BYTES) + w * (32 * PT_STRIDE);

    // Q fragments (B-operand layout; same bytes as A-layout): q = w*32+half*16+l16
    bf16x8 qfrag[2][4];
#pragma unroll
    for (int half = 0; half < 2; ++half) {
        const __bf16* qrow = qb + ((size_t)n * HW + i0 + w * 32 + half * 16 + l16) * CC;
#pragma unroll
        for (int ks = 0; ks < 4; ++ks)
            qfrag[half][ks] = *reinterpret_cast<const bf16x8*>(qrow + ks * 32 + quad * 8);
    }

    float m_i[2] = {-1e30f, -1e30f};
    float l_i[2] = {0.f, 0.f};
    floatx4 o_acc[2][8];   // O^T: col=q=l16 (per half), row=c=quad*4+r (+16h)
#pragma unroll
    for (int half = 0; half < 2; ++half)
#pragma unroll
        for (int h = 0; h < 8; ++h) o_acc[half][h] = (floatx4){0.f, 0.f, 0.f, 0.f};

    const __bf16* kbase = kb + (size_t)n * HW * CC;
    const __bf16* vbase = vb + (size_t)n * CC * HW;

    const int jbeg = split * KEYS_PER_SPLIT;
    const int jend = jbeg + KEYS_PER_SPLIT;

    const int jr = t >> 4, ch = t & 15;   // K staging: 16 rows/pass, 8 c/lane

    for (int j0 = jbeg; j0 < jend; j0 += 64) {
        // ---- stage K tile (64j x 128c) into LDS ----
        bf16x8 kst[4];
#pragma unroll
        for (int p = 0; p < 4; ++p)
            kst[p] = *reinterpret_cast<const bf16x8*>(
                kbase + (size_t)(j0 + p * 16 + jr) * CC + ch * 8);
        __syncthreads();
#pragma unroll
        for (int p = 0; p < 4; ++p)
            *reinterpret_cast<bf16x8*>(&Kt[(p * 16 + jr) * KT_STRIDE + ch * 8]) = kst[p];
        __syncthreads();

        // ---- S^T = K Q^T : col=q=l16, row=j=g*16+quad*4+r ----
        floatx4 s[2][4];
#pragma unroll
        for (int half = 0; half < 2; ++half)
#pragma unroll
            for (int g = 0; g < 4; ++g) s[half][g] = (floatx4){0.f, 0.f, 0.f, 0.f};
#pragma unroll
        for (int ks = 0; ks < 4; ++ks) {
#pragma unroll
            for (int g = 0; g < 4; ++g) {
                bf16x8 kf = *reinterpret_cast<const bf16x8*>(
                    &Kt[(g * 16 + l16) * KT_STRIDE + ks * 32 + quad * 8]);
                s[0][g] = __builtin_amdgcn_mfma_f32_16x16x32_bf16(kf, qfrag[0][ks], s[0][g], 0, 0, 0);
                s[1][g] = __builtin_amdgcn_mfma_f32_16x16x32_bf16(kf, qfrag[1][ks], s[1][g], 0, 0, 0);
            }
        }

        // ---- online softmax (per-lane scalar state, exp2 domain) ----
#pragma unroll
        for (int half = 0; half < 2; ++half) {
            float rm = fmaxf(fmaxf(fmaxf(s[half][0][0], s[half][0][1]),
                                   fmaxf(s[half][0][2], s[half][0][3])),
                             fmaxf(fmaxf(s[half][1][0], s[half][1][1]),
                                   fmaxf(s[half][1][2], s[half][1][3])));
            float rm2 = fmaxf(fmaxf(fmaxf(s[half][2][0], s[half][2][1]),
                                    fmaxf(s[half][2][2], s[half][2][3])),
                              fmaxf(fmaxf(s[half][3][0], s[half][3][1]),
                                    fmaxf(s[half][3][2], s[half][3][3])));
            rm = fmaxf(rm, rm2);
            rm = fmaxf(rm, __shfl_xor(rm, 16, 64));
            rm = fmaxf(rm, __shfl_xor(rm, 32, 64));
            if (__any(rm > m_i[half])) {          // wave-uniform rescale-skip
                float mn = fmaxf(m_i[half], rm);
                float alpha = exp2f(m_i[half] - mn);
                m_i[half] = mn;
                l_i[half] *= alpha;
#pragma unroll
                for (int h = 0; h < 8; ++h)
                    o_acc[half][h] *= alpha;
            }
            float mi = m_i[half];
            float rs = 0.f;
#pragma unroll
            for (int g = 0; g < 4; ++g)
#pragma unroll
                for (int r = 0; r < 4; ++r) {
                    float e = exp2f(s[half][g][r] - mi);
                    s[half][g][r] = e;
                    rs += e;
                }
            rs += __shfl_xor(rs, 16, 64);
            rs += __shfl_xor(rs, 32, 64);
            l_i[half] += rs;

            // P^T -> LDS: 4 consecutive j per lane -> one b64 write per g
#pragma unroll
            for (int g = 0; g < 4; ++g) {
                bf16x4 pk = {(__bf16)s[half][g][0], (__bf16)s[half][g][1],
                             (__bf16)s[half][g][2], (__bf16)s[half][g][3]};
                *reinterpret_cast<bf16x4*>(
                    &Pt[(half * 16 + l16) * PT_STRIDE + g * 16 + quad * 4]) = pk;
            }
        }

        // ---- O^T += V P^T : V frags direct from L2, P frags b128 from LDS ----
#pragma unroll
        for (int tt = 0; tt < 2; ++tt) {
            bf16x8 vf[8];
#pragma unroll
            for (int h = 0; h < 8; ++h)
                vf[h] = *reinterpret_cast<const bf16x8*>(
                    vbase + (size_t)(h * 16 + l16) * HW + j0 + tt * 32 + quad * 8);
            bf16x8 pf0 = *reinterpret_cast<const bf16x8*>(
                &Pt[l16 * PT_STRIDE + tt * 32 + quad * 8]);
            bf16x8 pf1 = *reinterpret_cast<const bf16x8*>(
                &Pt[(16 + l16) * PT_STRIDE + tt * 32 + quad * 8]);
#pragma unroll
            for (int h = 0; h < 8; ++h) {
                o_acc[0][h] = __builtin_amdgcn_mfma_f32_16x16x32_bf16(vf[h], pf0, o_acc[0][h], 0, 0, 0);
                o_acc[1][h] = __builtin_amdgcn_mfma_f32_16x16x32_bf16(vf[h], pf1, o_acc[1][h], 0, 0, 0);
            }
        }
    }

    // ---- (m, l) out: state replicated across quads; quad 0 writes ----
    if (quad == 0) {
#pragma unroll
        for (int half = 0; half < 2; ++half) {
            int q = w * 32 + half * 16 + l16;
            ml[(size_t)b * 256 + q]       = m_i[half];
            ml[(size_t)b * 256 + 128 + q] = l_i[half];
        }
    }

    float inv[2] = {1.f / l_i[0], 1.f / l_i[1]};

    // ---- epilogue: O^T/l -> LDS [c][q] -> bf16 opart (coalesced) ----
    __syncthreads();   // Kt dead
#pragma unroll
    for (int pass = 0; pass < 2; ++pass) {
        if ((w >> 1) == pass) {
            int ql = (w & 1) * 32;
#pragma unroll
            for (int half = 0; half < 2; ++half)
#pragma unroll
                for (int h = 0; h < 8; ++h)
#pragma unroll
                    for (int r = 0; r < 4; ++r)
                        T[(h * 16 + quad * 4 + r) * T_STRIDE + ql + half * 16 + l16] =
                            o_acc[half][h][r] * inv[half];
        }
        __syncthreads();
#pragma unroll 4
        for (int p = 0; p < 16; ++p) {
            int c  = p * 8 + (t >> 5);
            int q2 = (t & 31) * 2;
            float f0 = T[c * T_STRIDE + q2];
            float f1 = T[c * T_STRIDE + q2 + 1];
            bf16x2 pk = {(__bf16)f0, (__bf16)f1};
            *reinterpret_cast<bf16x2*>(
                &opart[(size_t)b * 16384 + (size_t)c * 128 + pass * 64 + q2]) = pk;
        }
        __syncthreads();
    }
}

// ---------------------------------------------------------------------------
// Combine: grid 1024 = qt(128) x cpart(8). Merge 4 splits (exp2 domain),
// out = gamma*O + x.
// ---------------------------------------------------------------------------
__global__ __launch_bounds__(256) void combine_kernel(
    const __bf16* __restrict__ opart, const float* __restrict__ ml,
    const float* __restrict__ x, const float* __restrict__ gamma,
    float* __restrict__ out)
{
    __shared__ float wsc[NSPLIT][128];

    const int b2    = blockIdx.x;
    const int cpart = b2 & 7;
    const int qt    = b2 >> 3;       // 0..127
    const int n     = qt >> 5;
    const int it    = qt & 31;
    const int i0    = it << 7;
    const int t     = threadIdx.x;
    const float gm  = gamma[0];

    int battn[NSPLIT];
#pragma unroll
    for (int s = 0; s < NSPLIT; ++s)
        battn[s] = (it << 4) | ((s >> 1) << 3) | (n << 1) | (s & 1);

    if (t < 128) {
        float ms[NSPLIT], ls[NSPLIT], M = -1e30f;
#pragma unroll
        for (int s = 0; s < NSPLIT; ++s) {
            ms[s] = ml[(size_t)battn[s] * 256 + t];
            ls[s] = ml[(size_t)battn[s] * 256 + 128 + t];
            M = fmaxf(M, ms[s]);
        }
        float denom = 0.f, es[NSPLIT];
#pragma unroll
        for (int s = 0; s < NSPLIT; ++s) {
            es[s] = exp2f(ms[s] - M);
            denom += es[s] * ls[s];
        }
        float inv = gm / denom;
#pragma unroll
        for (int s = 0; s < NSPLIT; ++s)
            wsc[s][t] = es[s] * inv;
    }
    __syncthreads();

#pragma unroll
    for (int p = 0; p < 4; ++p) {
        int c  = cpart * 16 + p * 4 + (t >> 6);
        int q2 = (t & 63) * 2;
        size_t gidx = ((size_t)n * CC + c) * HW + i0 + q2;
        float2 xv = *reinterpret_cast<const float2*>(&x[gidx]);
        float a0 = xv.x, a1 = xv.y;
#pragma unroll
        for (int s = 0; s < NSPLIT; ++s) {
            bf16x2 ov = *reinterpret_cast<const bf16x2*>(
                &opart[(size_t)battn[s] * 16384 + (size_t)c * 128 + q2]);
            a0 += wsc[s][q2]     * (float)ov[0];
            a1 += wsc[s][q2 + 1] * (float)ov[1];
        }
        float2 o2 = {a0, a1};
        *reinterpret_cast<float2*>(&out[gidx]) = o2;
    }
}

extern "C" void kernel_launch(void* const* d_in, const int* in_sizes, int n_in,
                              void* d_out, int out_size, void* d_ws, size_t ws_size,
                              hipStream_t stream) {
    const float* x     = (const float*)d_in[0];
    const float* wq    = (const float*)d_in[1];
    const float* bq    = (const float*)d_in[2];
    const float* wk    = (const float*)d_in[3];
    const float* bk    = (const float*)d_in[4];
    const float* wv    = (const float*)d_in[5];
    const float* bv    = (const float*)d_in[6];
    const float* gamma = (const float*)d_in[7];
    float* out = (float*)d_out;

    char* ws = (char*)d_ws;
    const size_t qkv_sz = (size_t)4 * HW * CC * sizeof(__bf16);    // 4 MB each
    __bf16* qb = (__bf16*)(ws);
    __bf16* kb = (__bf16*)(ws + qkv_sz);
    __bf16* vb = (__bf16*)(ws + 2 * qkv_sz);
    __bf16* wb = (__bf16*)(ws + 3 * qkv_sz);                       // 96 KB
    __bf16* opart = (__bf16*)(ws + 3 * qkv_sz + 3 * CC * CC * sizeof(__bf16));
    float* ml = (float*)((char*)opart + (size_t)512 * 16384 * sizeof(__bf16)); // 16 MB

    wconv_kernel<<<192, 256, 0, stream>>>(wq, wk, wv, wb);
    proj_kernel<<<768, 256, 0, stream>>>(x, wb, bq, bk, bv, qb, kb, vb);
    attn_split_kernel<<<512, 256, 0, stream>>>(qb, kb, vb, opart, ml);
    combine_kernel<<<1024, 256, 0, stream>>>(opart, ml, x, gamma, out);
}

// Round 5
// 144.554 us; speedup vs baseline: 1.3333x; 1.3333x over previous
//
#include <hip/hip_runtime.h>

#define HW 4096
#define CC 128
#define NSPLIT 4
#define KEYS_PER_SPLIT (HW / NSPLIT)
#define LOG2E 1.44269504088896f

typedef __bf16 bf16x8 __attribute__((ext_vector_type(8)));
typedef __bf16 bf16x4 __attribute__((ext_vector_type(4)));
typedef __bf16 bf16x2 __attribute__((ext_vector_type(2)));
typedef float floatx4 __attribute__((ext_vector_type(4)));

// ---------------------------------------------------------------------------
// Weight conversion: wq|wk|wv fp32 -> contiguous bf16 [3][128][128]
// ---------------------------------------------------------------------------
__global__ __launch_bounds__(256) void wconv_kernel(
    const float* __restrict__ wq, const float* __restrict__ wk,
    const float* __restrict__ wv, __bf16* __restrict__ wb)
{
    int idx = blockIdx.x * 256 + threadIdx.x;
    int which = idx >> 14;
    int within = idx & 16383;
    const float* src = (which == 0) ? wq : (which == 1) ? wk : wv;
    wb[idx] = (__bf16)src[within];
}

// ---------------------------------------------------------------------------
// Projection v2. Grid 1536 = (n*128+it)*3 + m, 32-pixel tiles (6 blocks/CU).
// float4 x loads -> bf16 LDS transpose -> 16 MFMA/wave, weights from L2-hot
// global. Q prescaled by log2(e). q,k -> [N][HW][C]; v -> [N][C][HW].
// ---------------------------------------------------------------------------
#define XT_STRIDE 136   // bf16; 272 B rows
#define VT2_STRIDE 40   // bf16; 80 B rows

__global__ __launch_bounds__(256, 4) void proj_kernel(
    const float* __restrict__ x, const __bf16* __restrict__ wb,
    const float* __restrict__ bq, const float* __restrict__ bk,
    const float* __restrict__ bv,
    __bf16* __restrict__ qb, __bf16* __restrict__ kb, __bf16* __restrict__ vb)
{
    __shared__ char smem_raw[128 * VT2_STRIDE * 2];     // 10240 B, unioned
    __bf16* Xt = reinterpret_cast<__bf16*>(smem_raw);   // [32 i][136]
    __bf16* Vt = reinterpret_cast<__bf16*>(smem_raw);   // [128 d][40]

    const int m   = blockIdx.x % 3;
    const int nit = blockIdx.x / 3;          // 0..511
    const int n   = nit >> 7;
    const int it  = nit & 127;
    const int i0  = it << 5;
    const int t   = threadIdx.x;

    const float* xb = x + (size_t)n * CC * HW;

    // stage x^T tile [32 i][128 c]: 4 float4 loads + 16 bf16 LDS writes/thread
    {
        const int f = t & 7;          // float4 index within 32-float row
        const int cb = t >> 3;        // 0..31
#pragma unroll
        for (int p = 0; p < 4; ++p) {
            int c = p * 32 + cb;
            float4 xv = *reinterpret_cast<const float4*>(&xb[(size_t)c * HW + i0 + f * 4]);
            Xt[(f * 4 + 0) * XT_STRIDE + c] = (__bf16)xv.x;
            Xt[(f * 4 + 1) * XT_STRIDE + c] = (__bf16)xv.y;
            Xt[(f * 4 + 2) * XT_STRIDE + c] = (__bf16)xv.z;
            Xt[(f * 4 + 3) * XT_STRIDE + c] = (__bf16)xv.w;
        }
    }
    __syncthreads();

    const int w    = t >> 6;
    const int lane = t & 63;
    const int l16  = lane & 15;
    const int quad = lane >> 4;
    const int d0   = w * 32;

    bf16x8 afrag[2][4];
#pragma unroll
    for (int it16 = 0; it16 < 2; ++it16)
#pragma unroll
        for (int ks = 0; ks < 4; ++ks)
            afrag[it16][ks] = *reinterpret_cast<const bf16x8*>(
                &Xt[(it16 * 16 + l16) * XT_STRIDE + ks * 32 + quad * 8]);

    const __bf16* wm = wb + (size_t)m * CC * CC;
    const float* Bm = (m == 0) ? bq : (m == 1) ? bk : bv;
    const float scale = (m == 0) ? LOG2E : 1.0f;

    floatx4 acc[2][2];
#pragma unroll
    for (int dt = 0; dt < 2; ++dt) {
        int d = d0 + dt * 16 + l16;
        bf16x8 bfrag[4];
#pragma unroll
        for (int ks = 0; ks < 4; ++ks)
            bfrag[ks] = *reinterpret_cast<const bf16x8*>(
                wm + (size_t)d * CC + ks * 32 + quad * 8);
#pragma unroll
        for (int it16 = 0; it16 < 2; ++it16) {
            acc[dt][it16] = (floatx4){0.f, 0.f, 0.f, 0.f};
#pragma unroll
            for (int ks = 0; ks < 4; ++ks)
                acc[dt][it16] = __builtin_amdgcn_mfma_f32_16x16x32_bf16(
                    afrag[it16][ks], bfrag[ks], acc[dt][it16], 0, 0, 0);
        }
    }

    if (m < 2) {
        __bf16* dst = (m == 0) ? qb : kb;
#pragma unroll
        for (int dt = 0; dt < 2; ++dt) {
            int d = d0 + dt * 16 + l16;
            float bias = Bm[d];
#pragma unroll
            for (int it16 = 0; it16 < 2; ++it16)
#pragma unroll
                for (int r = 0; r < 4; ++r) {
                    int i = i0 + it16 * 16 + quad * 4 + r;
                    dst[((size_t)n * HW + i) * CC + d] =
                        (__bf16)((acc[dt][it16][r] + bias) * scale);
                }
        }
    } else {
        __syncthreads();   // Xt dead before Vt overwrite
#pragma unroll
        for (int dt = 0; dt < 2; ++dt) {
            int d = d0 + dt * 16 + l16;
            float bias = Bm[d];
#pragma unroll
            for (int it16 = 0; it16 < 2; ++it16)
#pragma unroll
                for (int r = 0; r < 4; ++r)
                    Vt[d * VT2_STRIDE + it16 * 16 + quad * 4 + r] =
                        (__bf16)(acc[dt][it16][r] + bias);
        }
        __syncthreads();
        // store V rows coalesced: thread -> (d = t>>1, half = t&1), 16 bf16
        {
            int d = t >> 1, half = t & 1;
            bf16x8 v0 = *reinterpret_cast<const bf16x8*>(&Vt[d * VT2_STRIDE + half * 16]);
            bf16x8 v1 = *reinterpret_cast<const bf16x8*>(&Vt[d * VT2_STRIDE + half * 16 + 8]);
            __bf16* vp = vb + ((size_t)n * CC + d) * HW + i0 + half * 16;
            *reinterpret_cast<bf16x8*>(vp)     = v0;
            *reinterpret_cast<bf16x8*>(vp + 8) = v1;
        }
    }
}

// ---------------------------------------------------------------------------
// Flash attention, key-split. Grid 512, 128 q/block (32 q/wave), 2 blocks/CU.
// K AND V staged in LDS (shared by 4 waves). S in transposed orientation
// (s = mfma(K, Q)): col = q = l16 -> scalar softmax state, packed b64 P^T
// writes + b128 reads. exp2 domain. O^T accumulated [c][q]; bf16 opart.
// ---------------------------------------------------------------------------
#define KT_STRIDE 136                   // bf16; 272 B rows
#define KT_BYTES (64 * KT_STRIDE * 2)   // 17408
#define VT_STRIDE 72                    // bf16; 144 B rows
#define VT_BYTES (128 * VT_STRIDE * 2)  // 18432
#define P_OFF    (KT_BYTES + VT_BYTES)  // 35840
#define PT_STRIDE 72
#define PT_WAVE (32 * PT_STRIDE * 2)    // 4608 B per wave
#define T_STRIDE 65                     // fp32 epilogue [c][q]

__global__ __launch_bounds__(256, 2) void attn_split_kernel(
    const __bf16* __restrict__ qb, const __bf16* __restrict__ kb,
    const __bf16* __restrict__ vb,
    __bf16* __restrict__ opart, float* __restrict__ ml)
{
    __shared__ char smem[P_OFF + 4 * PT_WAVE];      // 54272 B
    __bf16* Kt = reinterpret_cast<__bf16*>(smem);
    __bf16* Vt = reinterpret_cast<__bf16*>(smem + KT_BYTES);
    float*  T  = reinterpret_cast<float*>(smem);    // epilogue alias [128][65]

    const int b     = blockIdx.x;
    const int n     = (b >> 1) & 3;
    const int split = (((b >> 3) & 1) << 1) | (b & 1);
    const int it    = b >> 4;                 // 0..31
    const int i0    = it << 7;                // *128
    const int t     = threadIdx.x;
    const int w     = t >> 6;
    const int lane  = t & 63;
    const int l16   = lane & 15;
    const int quad  = lane >> 4;

    __bf16* Pt = reinterpret_cast<__bf16*>(smem + P_OFF) + w * (32 * PT_STRIDE);

    // Q fragments (B-operand layout): q = w*32 + half*16 + l16
    bf16x8 qfrag[2][4];
#pragma unroll
    for (int half = 0; half < 2; ++half) {
        const __bf16* qrow = qb + ((size_t)n * HW + i0 + w * 32 + half * 16 + l16) * CC;
#pragma unroll
        for (int ks = 0; ks < 4; ++ks)
            qfrag[half][ks] = *reinterpret_cast<const bf16x8*>(qrow + ks * 32 + quad * 8);
    }

    float m_i[2] = {-1e30f, -1e30f};
    float l_i[2] = {0.f, 0.f};
    floatx4 o_acc[2][8];   // O^T: col=q=l16 (per half), row=c=h*16+quad*4+r
#pragma unroll
    for (int half = 0; half < 2; ++half)
#pragma unroll
        for (int h = 0; h < 8; ++h) o_acc[half][h] = (floatx4){0.f, 0.f, 0.f, 0.f};

    const __bf16* kbase = kb + (size_t)n * HW * CC;
    const __bf16* vbase = vb + (size_t)n * CC * HW;

    const int jbeg = split * KEYS_PER_SPLIT;
    const int jend = jbeg + KEYS_PER_SPLIT;

    const int jr = t >> 4, ch = t & 15;   // K staging map
    const int cv = t >> 3, ch2 = t & 7;   // V staging map

    for (int j0 = jbeg; j0 < jend; j0 += 64) {
        // ---- stage K (64j x 128c) and V (128c x 64j) into LDS ----
        bf16x8 kst[4], vst[4];
#pragma unroll
        for (int p = 0; p < 4; ++p) {
            kst[p] = *reinterpret_cast<const bf16x8*>(
                kbase + (size_t)(j0 + p * 16 + jr) * CC + ch * 8);
            vst[p] = *reinterpret_cast<const bf16x8*>(
                vbase + (size_t)(p * 32 + cv) * HW + j0 + ch2 * 8);
        }
        __syncthreads();   // previous iteration's readers done
#pragma unroll
        for (int p = 0; p < 4; ++p) {
            *reinterpret_cast<bf16x8*>(&Kt[(p * 16 + jr) * KT_STRIDE + ch * 8]) = kst[p];
            *reinterpret_cast<bf16x8*>(&Vt[(p * 32 + cv) * VT_STRIDE + ch2 * 8]) = vst[p];
        }
        __syncthreads();

        // ---- S^T = K Q^T : col=q=l16, row=j=g*16+quad*4+r ----
        floatx4 s[2][4];
#pragma unroll
        for (int half = 0; half < 2; ++half)
#pragma unroll
            for (int g = 0; g < 4; ++g) s[half][g] = (floatx4){0.f, 0.f, 0.f, 0.f};
#pragma unroll
        for (int ks = 0; ks < 4; ++ks) {
#pragma unroll
            for (int g = 0; g < 4; ++g) {
                bf16x8 kf = *reinterpret_cast<const bf16x8*>(
                    &Kt[(g * 16 + l16) * KT_STRIDE + ks * 32 + quad * 8]);
                s[0][g] = __builtin_amdgcn_mfma_f32_16x16x32_bf16(kf, qfrag[0][ks], s[0][g], 0, 0, 0);
                s[1][g] = __builtin_amdgcn_mfma_f32_16x16x32_bf16(kf, qfrag[1][ks], s[1][g], 0, 0, 0);
            }
        }

        // ---- online softmax (per-lane scalar state, exp2 domain) ----
#pragma unroll
        for (int half = 0; half < 2; ++half) {
            float rm = fmaxf(fmaxf(fmaxf(s[half][0][0], s[half][0][1]),
                                   fmaxf(s[half][0][2], s[half][0][3])),
                             fmaxf(fmaxf(s[half][1][0], s[half][1][1]),
                                   fmaxf(s[half][1][2], s[half][1][3])));
            float rm2 = fmaxf(fmaxf(fmaxf(s[half][2][0], s[half][2][1]),
                                    fmaxf(s[half][2][2], s[half][2][3])),
                              fmaxf(fmaxf(s[half][3][0], s[half][3][1]),
                                    fmaxf(s[half][3][2], s[half][3][3])));
            rm = fmaxf(rm, rm2);
            rm = fmaxf(rm, __shfl_xor(rm, 16, 64));
            rm = fmaxf(rm, __shfl_xor(rm, 32, 64));
            if (__any(rm > m_i[half])) {          // wave-uniform rescale-skip
                float mn = fmaxf(m_i[half], rm);
                float alpha = exp2f(m_i[half] - mn);
                m_i[half] = mn;
                l_i[half] *= alpha;
#pragma unroll
                for (int h = 0; h < 8; ++h)
                    o_acc[half][h] *= alpha;
            }
            float mi = m_i[half];
            float rs = 0.f;
#pragma unroll
            for (int g = 0; g < 4; ++g)
#pragma unroll
                for (int r = 0; r < 4; ++r) {
                    float e = exp2f(s[half][g][r] - mi);
                    s[half][g][r] = e;
                    rs += e;
                }
            rs += __shfl_xor(rs, 16, 64);
            rs += __shfl_xor(rs, 32, 64);
            l_i[half] += rs;

            // P^T -> LDS: 4 consecutive j per lane -> one b64 write per g
#pragma unroll
            for (int g = 0; g < 4; ++g) {
                bf16x4 pk = {(__bf16)s[half][g][0], (__bf16)s[half][g][1],
                             (__bf16)s[half][g][2], (__bf16)s[half][g][3]};
                *reinterpret_cast<bf16x4*>(
                    &Pt[(half * 16 + l16) * PT_STRIDE + g * 16 + quad * 4]) = pk;
            }
        }

        // ---- O^T += V P^T : V frags from LDS, shared across halves ----
#pragma unroll
        for (int tt = 0; tt < 2; ++tt) {
            bf16x8 pf0 = *reinterpret_cast<const bf16x8*>(
                &Pt[l16 * PT_STRIDE + tt * 32 + quad * 8]);
            bf16x8 pf1 = *reinterpret_cast<const bf16x8*>(
                &Pt[(16 + l16) * PT_STRIDE + tt * 32 + quad * 8]);
#pragma unroll
            for (int h = 0; h < 8; ++h) {
                bf16x8 vf = *reinterpret_cast<const bf16x8*>(
                    &Vt[(h * 16 + l16) * VT_STRIDE + tt * 32 + quad * 8]);
                o_acc[0][h] = __builtin_amdgcn_mfma_f32_16x16x32_bf16(vf, pf0, o_acc[0][h], 0, 0, 0);
                o_acc[1][h] = __builtin_amdgcn_mfma_f32_16x16x32_bf16(vf, pf1, o_acc[1][h], 0, 0, 0);
            }
        }
    }

    // ---- (m, l) out: state replicated across quads; quad 0 writes ----
    if (quad == 0) {
#pragma unroll
        for (int half = 0; half < 2; ++half) {
            int q = w * 32 + half * 16 + l16;
            ml[(size_t)b * 256 + q]       = m_i[half];
            ml[(size_t)b * 256 + 128 + q] = l_i[half];
        }
    }

    float inv[2] = {1.f / l_i[0], 1.f / l_i[1]};

    // ---- epilogue: O^T/l -> LDS [c][q] -> bf16 opart (coalesced) ----
    __syncthreads();   // Kt/Vt dead
#pragma unroll
    for (int pass = 0; pass < 2; ++pass) {
        if ((w >> 1) == pass) {
            int ql = (w & 1) * 32;
#pragma unroll
            for (int half = 0; half < 2; ++half)
#pragma unroll
                for (int h = 0; h < 8; ++h)
#pragma unroll
                    for (int r = 0; r < 4; ++r)
                        T[(h * 16 + quad * 4 + r) * T_STRIDE + ql + half * 16 + l16] =
                            o_acc[half][h][r] * inv[half];
        }
        __syncthreads();
#pragma unroll 4
        for (int p = 0; p < 16; ++p) {
            int c  = p * 8 + (t >> 5);
            int q2 = (t & 31) * 2;
            float f0 = T[c * T_STRIDE + q2];
            float f1 = T[c * T_STRIDE + q2 + 1];
            bf16x2 pk = {(__bf16)f0, (__bf16)f1};
            *reinterpret_cast<bf16x2*>(
                &opart[(size_t)b * 16384 + (size_t)c * 128 + pass * 64 + q2]) = pk;
        }
        __syncthreads();
    }
}

// ---------------------------------------------------------------------------
// Combine: grid 1024 = qt(128) x cpart(8). Merge 4 splits (exp2 domain),
// out = gamma*O + x.
// ---------------------------------------------------------------------------
__global__ __launch_bounds__(256) void combine_kernel(
    const __bf16* __restrict__ opart, const float* __restrict__ ml,
    const float* __restrict__ x, const float* __restrict__ gamma,
    float* __restrict__ out)
{
    __shared__ float wsc[NSPLIT][128];

    const int b2    = blockIdx.x;
    const int cpart = b2 & 7;
    const int qt    = b2 >> 3;       // 0..127
    const int n     = qt >> 5;
    const int it    = qt & 31;
    const int i0    = it << 7;
    const int t     = threadIdx.x;
    const float gm  = gamma[0];

    int battn[NSPLIT];
#pragma unroll
    for (int s = 0; s < NSPLIT; ++s)
        battn[s] = (it << 4) | ((s >> 1) << 3) | (n << 1) | (s & 1);

    if (t < 128) {
        float ms[NSPLIT], ls[NSPLIT], M = -1e30f;
#pragma unroll
        for (int s = 0; s < NSPLIT; ++s) {
            ms[s] = ml[(size_t)battn[s] * 256 + t];
            ls[s] = ml[(size_t)battn[s] * 256 + 128 + t];
            M = fmaxf(M, ms[s]);
        }
        float denom = 0.f, es[NSPLIT];
#pragma unroll
        for (int s = 0; s < NSPLIT; ++s) {
            es[s] = exp2f(ms[s] - M);
            denom += es[s] * ls[s];
        }
        float inv = gm / denom;
#pragma unroll
        for (int s = 0; s < NSPLIT; ++s)
            wsc[s][t] = es[s] * inv;
    }
    __syncthreads();

#pragma unroll
    for (int p = 0; p < 4; ++p) {
        int c  = cpart * 16 + p * 4 + (t >> 6);
        int q2 = (t & 63) * 2;
        size_t gidx = ((size_t)n * CC + c) * HW + i0 + q2;
        float2 xv = *reinterpret_cast<const float2*>(&x[gidx]);
        float a0 = xv.x, a1 = xv.y;
#pragma unroll
        for (int s = 0; s < NSPLIT; ++s) {
            bf16x2 ov = *reinterpret_cast<const bf16x2*>(
                &opart[(size_t)battn[s] * 16384 + (size_t)c * 128 + q2]);
            a0 += wsc[s][q2]     * (float)ov[0];
            a1 += wsc[s][q2 + 1] * (float)ov[1];
        }
        float2 o2 = {a0, a1};
        *reinterpret_cast<float2*>(&out[gidx]) = o2;
    }
}

extern "C" void kernel_launch(void* const* d_in, const int* in_sizes, int n_in,
                              void* d_out, int out_size, void* d_ws, size_t ws_size,
                              hipStream_t stream) {
    const float* x     = (const float*)d_in[0];
    const float* wq    = (const float*)d_in[1];
    const float* bq    = (const float*)d_in[2];
    const float* wk    = (const float*)d_in[3];
    const float* bk    = (const float*)d_in[4];
    const float* wv    = (const float*)d_in[5];
    const float* bv    = (const float*)d_in[6];
    const float* gamma = (const float*)d_in[7];
    float* out = (float*)d_out;

    char* ws = (char*)d_ws;
    const size_t qkv_sz = (size_t)4 * HW * CC * sizeof(__bf16);    // 4 MB each
    __bf16* qb = (__bf16*)(ws);
    __bf16* kb = (__bf16*)(ws + qkv_sz);
    __bf16* vb = (__bf16*)(ws + 2 * qkv_sz);
    __bf16* wb = (__bf16*)(ws + 3 * qkv_sz);                       // 96 KB
    __bf16* opart = (__bf16*)(ws + 3 * qkv_sz + 3 * CC * CC * sizeof(__bf16));
    float* ml = (float*)((char*)opart + (size_t)512 * 16384 * sizeof(__bf16)); // 16 MB

    wconv_kernel<<<192, 256, 0, stream>>>(wq, wk, wv, wb);
    proj_kernel<<<1536, 256, 0, stream>>>(x, wb, bq, bk, bv, qb, kb, vb);
    attn_split_kernel<<<512, 256, 0, stream>>>(qb, kb, vb, opart, ml);
    combine_kernel<<<1024, 256, 0, stream>>>(opart, ml, x, gamma, out);
}

// Round 8
// 142.768 us; speedup vs baseline: 1.3500x; 1.0125x over previous
//
#include <hip/hip_runtime.h>

#define HW 4096
#define CC 128
#define NSPLIT 4
#define KPS (HW / NSPLIT)   // 1024 keys per split
#define NJ (KPS / 64)       // 16 j-iterations
#define LOG2E 1.44269504088896f

typedef __bf16 bf16x8 __attribute__((ext_vector_type(8)));
typedef __bf16 bf16x4 __attribute__((ext_vector_type(4)));
typedef __bf16 bf16x2 __attribute__((ext_vector_type(2)));
typedef float floatx4 __attribute__((ext_vector_type(4)));

#define AS1 __attribute__((address_space(1)))
#define AS3 __attribute__((address_space(3)))

// global->LDS DMA, 16 B/lane. HW semantics: wave-uniform base + lane*16; we
// pass base+tid*16 whose wave-uniform part + lane*16 equals the same address.
__device__ __forceinline__ void dma16(const __bf16* g, char* l) {
    __builtin_amdgcn_global_load_lds((const AS1 void*)g, (AS3 void*)l, 16, 0, 0);
}

// ---------------------------------------------------------------------------
// Weight conversion: wq|wk|wv fp32 -> contiguous bf16 [3][128][128]
// ---------------------------------------------------------------------------
__global__ __launch_bounds__(256) void wconv_kernel(
    const float* __restrict__ wq, const float* __restrict__ wk,
    const float* __restrict__ wv, __bf16* __restrict__ wb)
{
    int idx = blockIdx.x * 256 + threadIdx.x;
    int which = idx >> 14;
    int within = idx & 16383;
    const float* src = (which == 0) ? wq : (which == 1) ? wk : wv;
    wb[idx] = (__bf16)src[within];
}

// ---------------------------------------------------------------------------
// Projection (R5, unchanged). Grid 1536 = (n*128+it)*3 + m, 32-pixel tiles.
// Q prescaled by log2(e). q,k -> [N][HW][C]; v -> [N][C][HW].
// ---------------------------------------------------------------------------
#define XT_STRIDE 136
#define VT2_STRIDE 40

__global__ __launch_bounds__(256, 4) void proj_kernel(
    const float* __restrict__ x, const __bf16* __restrict__ wb,
    const float* __restrict__ bq, const float* __restrict__ bk,
    const float* __restrict__ bv,
    __bf16* __restrict__ qb, __bf16* __restrict__ kb, __bf16* __restrict__ vb)
{
    __shared__ char smem_raw[128 * VT2_STRIDE * 2];
    __bf16* Xt = reinterpret_cast<__bf16*>(smem_raw);   // [32 i][136]
    __bf16* Vt = reinterpret_cast<__bf16*>(smem_raw);   // [128 d][40]

    const int m   = blockIdx.x % 3;
    const int nit = blockIdx.x / 3;
    const int n   = nit >> 7;
    const int i0  = (nit & 127) << 5;
    const int t   = threadIdx.x;

    const float* xb = x + (size_t)n * CC * HW;

    {
        const int f = t & 7, cb = t >> 3;
#pragma unroll
        for (int p = 0; p < 4; ++p) {
            int c = p * 32 + cb;
            float4 xv = *(const float4*)(&xb[(size_t)c * HW + i0 + f * 4]);
            Xt[(f * 4 + 0) * XT_STRIDE + c] = (__bf16)xv.x;
            Xt[(f * 4 + 1) * XT_STRIDE + c] = (__bf16)xv.y;
            Xt[(f * 4 + 2) * XT_STRIDE + c] = (__bf16)xv.z;
            Xt[(f * 4 + 3) * XT_STRIDE + c] = (__bf16)xv.w;
        }
    }
    __syncthreads();

    const int w    = t >> 6;
    const int lane = t & 63;
    const int l16  = lane & 15;
    const int quad = lane >> 4;
    const int d0   = w * 32;

    bf16x8 afrag[2][4];
#pragma unroll
    for (int it16 = 0; it16 < 2; ++it16)
#pragma unroll
        for (int ks = 0; ks < 4; ++ks)
            afrag[it16][ks] = *(const bf16x8*)(
                &Xt[(it16 * 16 + l16) * XT_STRIDE + ks * 32 + quad * 8]);

    const __bf16* wm = wb + (size_t)m * CC * CC;
    const float* Bm = (m == 0) ? bq : (m == 1) ? bk : bv;
    const float scale = (m == 0) ? LOG2E : 1.0f;

    floatx4 acc[2][2];
#pragma unroll
    for (int dt = 0; dt < 2; ++dt) {
        int d = d0 + dt * 16 + l16;
        bf16x8 bfrag[4];
#pragma unroll
        for (int ks = 0; ks < 4; ++ks)
            bfrag[ks] = *(const bf16x8*)(wm + (size_t)d * CC + ks * 32 + quad * 8);
#pragma unroll
        for (int it16 = 0; it16 < 2; ++it16) {
            acc[dt][it16] = (floatx4){0.f, 0.f, 0.f, 0.f};
#pragma unroll
            for (int ks = 0; ks < 4; ++ks)
                acc[dt][it16] = __builtin_amdgcn_mfma_f32_16x16x32_bf16(
                    afrag[it16][ks], bfrag[ks], acc[dt][it16], 0, 0, 0);
        }
    }

    if (m < 2) {
        __bf16* dst = (m == 0) ? qb : kb;
#pragma unroll
        for (int dt = 0; dt < 2; ++dt) {
            int d = d0 + dt * 16 + l16;
            float bias = Bm[d];
#pragma unroll
            for (int it16 = 0; it16 < 2; ++it16)
#pragma unroll
                for (int r = 0; r < 4; ++r) {
                    int i = i0 + it16 * 16 + quad * 4 + r;
                    dst[((size_t)n * HW + i) * CC + d] =
                        (__bf16)((acc[dt][it16][r] + bias) * scale);
                }
        }
    } else {
        __syncthreads();
#pragma unroll
        for (int dt = 0; dt < 2; ++dt) {
            int d = d0 + dt * 16 + l16;
            float bias = Bm[d];
#pragma unroll
            for (int it16 = 0; it16 < 2; ++it16)
#pragma unroll
                for (int r = 0; r < 4; ++r)
                    Vt[d * VT2_STRIDE + it16 * 16 + quad * 4 + r] =
                        (__bf16)(acc[dt][it16][r] + bias);
        }
        __syncthreads();
        {
            int d = t >> 1, half = t & 1;
            bf16x8 v0 = *(const bf16x8*)(&Vt[d * VT2_STRIDE + half * 16]);
            bf16x8 v1 = *(const bf16x8*)(&Vt[d * VT2_STRIDE + half * 16 + 8]);
            __bf16* vp = vb + ((size_t)n * CC + d) * HW + i0 + half * 16;
            *(bf16x8*)vp = v0;
            *(bf16x8*)(vp + 8) = v1;
        }
    }
}

// ---------------------------------------------------------------------------
// Flash attention, key-split. Grid 512, 128 q/block (32 q/wave), 2 blocks/CU.
// Staging via global_load_lds DMA (width 16): K single-buffered (16 KB),
// V double-buffered (2x16 KB), XOR-swizzled unpadded tiles. Pipeline:
//   top barrier: drains K(jt)+V(jt) DMA -> issue V(jt+1) -> S^T (covers it)
//   mid barrier: K readers done       -> issue K(jt+1) -> softmax+PV (covers)
// S transposed (s = mfma(K,Q)): scalar softmax state, b64 P writes. exp2.
// LDS total 57344 B (< 64 KiB workgroup limit — 73728 B failed to launch, R7).
// ---------------------------------------------------------------------------
#define SMEM_BYTES 57344
#define VT_OFF 16384
#define P_OFF  49152

__global__ __launch_bounds__(256, 2) void attn_split_kernel(
    const __bf16* __restrict__ qb, const __bf16* __restrict__ kb,
    const __bf16* __restrict__ vb,
    __bf16* __restrict__ opart, float* __restrict__ ml)
{
    __shared__ __align__(16) char smem[SMEM_BYTES];

    const int b     = blockIdx.x;
    const int n     = (b >> 1) & 3;
    const int split = (((b >> 3) & 1) << 1) | (b & 1);
    const int itq   = b >> 4;                 // 0..31
    const int i0    = itq << 7;               // 128 q per block
    const int t     = threadIdx.x;
    const int w     = t >> 6;
    const int lane  = t & 63;
    const int l16   = lane & 15;
    const int quad  = lane >> 4;

    char* Pw = smem + P_OFF + w * 2048;       // 16 rows x 128 B, per wave

    const int jbeg = split * KPS;
    const __bf16* kpane = kb + ((size_t)n * HW + jbeg) * CC;
    const __bf16* vpane = vb + (size_t)n * CC * HW + jbeg;

    // Q fragments (B-operand): q = w*32 + half*16 + l16 (prescaled log2e)
    bf16x8 qfrag[2][4];
#pragma unroll
    for (int half = 0; half < 2; ++half) {
        const __bf16* qr = qb + ((size_t)n * HW + i0 + w * 32 + half * 16 + l16) * CC;
#pragma unroll
        for (int ks = 0; ks < 4; ++ks)
            qfrag[half][ks] = *(const bf16x8*)(qr + ks * 32 + quad * 8);
    }

    float m_i[2] = {-1e30f, -1e30f};
    float l_i[2] = {0.f, 0.f};
    floatx4 o_acc[2][8];   // O^T: col=q=l16 (per half), row=c=h*16+quad*4+r
#pragma unroll
    for (int half = 0; half < 2; ++half)
#pragma unroll
        for (int h = 0; h < 8; ++h) o_acc[half][h] = (floatx4){0.f, 0.f, 0.f, 0.f};

    // swizzled fragment column offsets (bf16 elements)
    int kcol[4], vcol[2];
#pragma unroll
    for (int ks = 0; ks < 4; ++ks) kcol[ks] = ((ks * 4 + quad) ^ l16) * 8;
#pragma unroll
    for (int tt = 0; tt < 2; ++tt) vcol[tt] = ((tt * 4 + quad) ^ (l16 & 7)) * 8;

    // K tile: row j (0..63) x 256 B, block swizzle b ^= (j&15); write side
    // collapses to dest = p*4096 + t*16 with row p*16+(t>>4), blk (t&15)^((t>>4)&15)
    auto stageK = [&](int j0) {
#pragma unroll
        for (int p = 0; p < 4; ++p) {
            int krow  = p * 16 + (t >> 4);
            int kgblk = (t & 15) ^ ((t >> 4) & 15);
            dma16(kpane + (size_t)(j0 + krow) * CC + kgblk * 8,
                  smem + p * 4096 + t * 16);
        }
    };
    // V tile: row c (0..127) x 128 B, block swizzle b ^= (c&7)
    auto stageV = [&](int j0, int buf) {
        char* vd = smem + VT_OFF + buf * 16384;
#pragma unroll
        for (int p = 0; p < 4; ++p) {
            int vrow  = p * 32 + (t >> 3);
            int vgblk = (t & 7) ^ ((t >> 3) & 7);
            dma16(vpane + (size_t)vrow * HW + j0 + vgblk * 8,
                  vd + p * 4096 + t * 16);
        }
    };

    stageK(0);
    stageV(0, 0);
    int cur = 0;

    for (int jt = 0; jt < NJ; ++jt) {
        __syncthreads();   // drains K(jt)+V(jt) DMAs; prev iter readers done
        if (jt + 1 < NJ) stageV((jt + 1) * 64, cur ^ 1);

        const __bf16* Kc = (const __bf16*)smem;

        // ---- S^T = K Q^T (col=q=l16, row=j=g*16+quad*4+r) ----
        floatx4 s[2][4];
#pragma unroll
        for (int hh = 0; hh < 2; ++hh)
#pragma unroll
            for (int g = 0; g < 4; ++g) s[hh][g] = (floatx4){0.f, 0.f, 0.f, 0.f};
#pragma unroll
        for (int ks = 0; ks < 4; ++ks) {
#pragma unroll
            for (int g = 0; g < 4; ++g) {
                bf16x8 kf = *(const bf16x8*)(Kc + (g * 16 + l16) * 128 + kcol[ks]);
                s[0][g] = __builtin_amdgcn_mfma_f32_16x16x32_bf16(kf, qfrag[0][ks], s[0][g], 0, 0, 0);
                s[1][g] = __builtin_amdgcn_mfma_f32_16x16x32_bf16(kf, qfrag[1][ks], s[1][g], 0, 0, 0);
            }
        }

        __syncthreads();   // all waves done reading K; V(jt+1) DMA also drained
        if (jt + 1 < NJ) stageK((jt + 1) * 64);   // covered by softmax+PV

        // ---- online softmax (per-lane scalar state, exp2 domain) ----
        bf16x8 pf[2][2];
#pragma unroll
        for (int hh = 0; hh < 2; ++hh) {
            float rm = fmaxf(fmaxf(fmaxf(s[hh][0][0], s[hh][0][1]),
                                   fmaxf(s[hh][0][2], s[hh][0][3])),
                             fmaxf(fmaxf(s[hh][1][0], s[hh][1][1]),
                                   fmaxf(s[hh][1][2], s[hh][1][3])));
            float rm2 = fmaxf(fmaxf(fmaxf(s[hh][2][0], s[hh][2][1]),
                                    fmaxf(s[hh][2][2], s[hh][2][3])),
                              fmaxf(fmaxf(s[hh][3][0], s[hh][3][1]),
                                    fmaxf(s[hh][3][2], s[hh][3][3])));
            rm = fmaxf(rm, rm2);
            rm = fmaxf(rm, __shfl_xor(rm, 16, 64));
            rm = fmaxf(rm, __shfl_xor(rm, 32, 64));
            if (__any(rm > m_i[hh])) {
                float mn = fmaxf(m_i[hh], rm);
                float alpha = exp2f(m_i[hh] - mn);
                m_i[hh] = mn;
                l_i[hh] *= alpha;
#pragma unroll
                for (int h = 0; h < 8; ++h) o_acc[hh][h] *= alpha;
            }
            float mi = m_i[hh], rs = 0.f;
#pragma unroll
            for (int g = 0; g < 4; ++g)
#pragma unroll
                for (int r = 0; r < 4; ++r) {
                    float e = exp2f(s[hh][g][r] - mi);
                    s[hh][g][r] = e;
                    rs += e;
                }
            rs += __shfl_xor(rs, 16, 64);
            rs += __shfl_xor(rs, 32, 64);
            l_i[hh] += rs;

            // P write: row q=l16, swizzled 16B blocks, b64 per g
#pragma unroll
            for (int g = 0; g < 4; ++g) {
                bf16x4 pk = {(__bf16)s[hh][g][0], (__bf16)s[hh][g][1],
                             (__bf16)s[hh][g][2], (__bf16)s[hh][g][3]};
                int lblk = (g * 2 + (quad >> 1)) ^ (l16 & 7);
                *(bf16x4*)(Pw + l16 * 128 + lblk * 16 + (quad & 1) * 8) = pk;
            }
#pragma unroll
            for (int tt = 0; tt < 2; ++tt) {
                int rblk = (tt * 4 + quad) ^ (l16 & 7);
                pf[hh][tt] = *(const bf16x8*)(Pw + l16 * 128 + rblk * 16);
            }
        }

        // ---- O^T += V P^T : vf shared by both halves ----
        const __bf16* Vc = (const __bf16*)(smem + VT_OFF + cur * 16384);
#pragma unroll
        for (int tt = 0; tt < 2; ++tt) {
#pragma unroll
            for (int h = 0; h < 8; ++h) {
                bf16x8 vf = *(const bf16x8*)(Vc + (h * 16 + l16) * 64 + vcol[tt]);
                o_acc[0][h] = __builtin_amdgcn_mfma_f32_16x16x32_bf16(vf, pf[0][tt], o_acc[0][h], 0, 0, 0);
                o_acc[1][h] = __builtin_amdgcn_mfma_f32_16x16x32_bf16(vf, pf[1][tt], o_acc[1][h], 0, 0, 0);
            }
        }
        cur ^= 1;
    }

    // ---- (m,l) out ----
    if (quad == 0) {
#pragma unroll
        for (int half = 0; half < 2; ++half) {
            int q = w * 32 + half * 16 + l16;
            ml[(size_t)b * 256 + q]       = m_i[half];
            ml[(size_t)b * 256 + 128 + q] = l_i[half];
        }
    }
    float linv[2] = {1.f / l_i[0], 1.f / l_i[1]};

    // ---- epilogue: O^T/l -> LDS [c][q] fp32 -> bf16 opart (coalesced) ----
    __syncthreads();
    float* T = (float*)smem;                  // [128][65]
#pragma unroll
    for (int pass = 0; pass < 2; ++pass) {
        if ((w >> 1) == pass) {
            int ql = (w & 1) * 32;
#pragma unroll
            for (int half = 0; half < 2; ++half)
#pragma unroll
                for (int h = 0; h < 8; ++h)
#pragma unroll
                    for (int r = 0; r < 4; ++r)
                        T[(h * 16 + quad * 4 + r) * 65 + ql + half * 16 + l16] =
                            o_acc[half][h][r] * linv[half];
        }
        __syncthreads();
#pragma unroll 4
        for (int p = 0; p < 16; ++p) {
            int c  = p * 8 + (t >> 5);
            int q2 = (t & 31) * 2;
            bf16x2 pk = {(__bf16)T[c * 65 + q2], (__bf16)T[c * 65 + q2 + 1]};
            *(bf16x2*)(&opart[(size_t)b * 16384 + (size_t)c * 128 + pass * 64 + q2]) = pk;
        }
        __syncthreads();
    }
}

// ---------------------------------------------------------------------------
// Combine (R5, unchanged): grid 1024 = qt(128) x cpart(8).
// ---------------------------------------------------------------------------
__global__ __launch_bounds__(256) void combine_kernel(
    const __bf16* __restrict__ opart, const float* __restrict__ ml,
    const float* __restrict__ x, const float* __restrict__ gamma,
    float* __restrict__ out)
{
    __shared__ float wsc[NSPLIT][128];

    const int b2    = blockIdx.x;
    const int cpart = b2 & 7;
    const int qt    = b2 >> 3;
    const int n     = qt >> 5;
    const int it    = qt & 31;
    const int i0    = it << 7;
    const int t     = threadIdx.x;
    const float gm  = gamma[0];

    int battn[NSPLIT];
#pragma unroll
    for (int s = 0; s < NSPLIT; ++s)
        battn[s] = (it << 4) | ((s >> 1) << 3) | (n << 1) | (s & 1);

    if (t < 128) {
        float ms[NSPLIT], ls[NSPLIT], M = -1e30f;
#pragma unroll
        for (int s = 0; s < NSPLIT; ++s) {
            ms[s] = ml[(size_t)battn[s] * 256 + t];
            ls[s] = ml[(size_t)battn[s] * 256 + 128 + t];
            M = fmaxf(M, ms[s]);
        }
        float denom = 0.f, es[NSPLIT];
#pragma unroll
        for (int s = 0; s < NSPLIT; ++s) {
            es[s] = exp2f(ms[s] - M);
            denom += es[s] * ls[s];
        }
        float inv = gm / denom;
#pragma unroll
        for (int s = 0; s < NSPLIT; ++s)
            wsc[s][t] = es[s] * inv;
    }
    __syncthreads();

#pragma unroll
    for (int p = 0; p < 4; ++p) {
        int c  = cpart * 16 + p * 4 + (t >> 6);
        int q2 = (t & 63) * 2;
        size_t gidx = ((size_t)n * CC + c) * HW + i0 + q2;
        float2 xv = *(const float2*)(&x[gidx]);
        float a0 = xv.x, a1 = xv.y;
#pragma unroll
        for (int s = 0; s < NSPLIT; ++s) {
            bf16x2 ov = *(const bf16x2*)(
                &opart[(size_t)battn[s] * 16384 + (size_t)c * 128 + q2]);
            a0 += wsc[s][q2]     * (float)ov[0];
            a1 += wsc[s][q2 + 1] * (float)ov[1];
        }
        float2 o2;
        o2.x = a0; o2.y = a1;
        *(float2*)(&out[gidx]) = o2;
    }
}

extern "C" void kernel_launch(void* const* d_in, const int* in_sizes, int n_in,
                              void* d_out, int out_size, void* d_ws, size_t ws_size,
                              hipStream_t stream) {
    const float* x     = (const float*)d_in[0];
    const float* wq    = (const float*)d_in[1];
    const float* bq    = (const float*)d_in[2];
    const float* wk    = (const float*)d_in[3];
    const float* bk    = (const float*)d_in[4];
    const float* wv    = (const float*)d_in[5];
    const float* bv    = (const float*)d_in[6];
    const float* gamma = (const float*)d_in[7];
    float* out = (float*)d_out;

    char* ws = (char*)d_ws;
    const size_t qkv_sz = (size_t)4 * HW * CC * sizeof(__bf16);    // 4 MB each
    __bf16* qb = (__bf16*)(ws);
    __bf16* kb = (__bf16*)(ws + qkv_sz);
    __bf16* vb = (__bf16*)(ws + 2 * qkv_sz);
    __bf16* wb = (__bf16*)(ws + 3 * qkv_sz);                       // 96 KB
    __bf16* opart = (__bf16*)(ws + 3 * qkv_sz + 3 * CC * CC * sizeof(__bf16)); // 16 MB
    float* ml = (float*)((char*)opart + (size_t)512 * 16384 * sizeof(__bf16)); // 512 KB

    wconv_kernel<<<192, 256, 0, stream>>>(wq, wk, wv, wb);
    proj_kernel<<<1536, 256, 0, stream>>>(x, wb, bq, bk, bv, qb, kb, vb);
    attn_split_kernel<<<512, 256, 0, stream>>>(qb, kb, vb, opart, ml);
    combine_kernel<<<1024, 256, 0, stream>>>(opart, ml, x, gamma, out);
}